// Round 3
// baseline (15387.996 us; speedup 1.0000x reference)
//
#include <hip/hip_runtime.h>

typedef float f4 __attribute__((ext_vector_type(4)));

#define NT 256
#define BB 128
#define BT 100
#define DZc 64
#define DAc 32
#define DUc 8
#define KMIX 8
#define DOBSc 16
#define HG 128
#define DINc 56   // DA + DOBS + DU

// flat element offsets into d_out (return order of the reference tuple)
#define O_ZFILT   0LL
#define O_PFILT   819200LL
#define O_ZPRED   53248000LL
#define O_AFILT   54067200LL
#define O_APRED   54476800LL
#define O_PPRED   54886400LL
#define O_ALPHA   107315200LL
#define O_ASEQ    107417600LL
#define O_BSEQ    159846400LL
#define O_CSEQ    166400000LL
#define O_ZMEAN   192614400LL
#define O_LTRIL   193433600LL
#define O_SPRED   245862400LL

__device__ __forceinline__ float dot4(f4 a, f4 b) {
    return a[0]*b[0] + a[1]*b[1] + a[2]*b[2] + a[3]*b[3];
}

struct SMem {
    float P[DZc][68];     // covariance carry (P_pred -> P_filt -> P_pred)
    float A[DZc][68];     // mixed A
    float Wk[DZc][68];    // temp: G = X^T CP ; then A@P_filt
    float Qm[DZc][68];    // Q cached
    float C[DAc][68];     // mixed C
    float CP[DAc][68];    // C@P (kept raw through the solve)
    float Xm[DAc][68];    // X = S^{-1} C P
    float S[DAc][33];     // innovation cov -> LDL^T (raw cols + D on diag)
    float Rm[DAc][33];    // R cached
    float dinv[DAc];
    float Bm[DZc][8];     // mixed B
    float z[DZc], zp[DZc], zn[DZc];
    float h[HG];
    float gh[3*HG], gi[3*HG], gip[3*HG];
    float x[64];          // [ak(32) | h_obs(16) | u(8)]
    float ak[DAc], rvec[DAc];
    float u[8];
    float mk;
};

template<bool EMIT>
__device__ __forceinline__ void mix_apply(SMem& s, int tid, size_t bt, const float* al8,
    const float* __restrict__ A_mats, const float* __restrict__ B_mats,
    const float* __restrict__ C_mats, float* __restrict__ out)
{
    const f4* A4 = (const f4*)A_mats;
    const f4* B4 = (const f4*)B_mats;
    const f4* C4 = (const f4*)C_mats;
    #pragma unroll
    for (int e = 0; e < 4; ++e) {
        int i4 = tid + e*256;
        f4 acc = {0.f,0.f,0.f,0.f};
        #pragma unroll
        for (int k = 0; k < 8; ++k) acc += al8[k] * A4[k*1024 + i4];
        *(f4*)&s.A[i4>>4][(i4&15)*4] = acc;
        if (EMIT) *(f4*)&out[O_ASEQ + bt*4096 + (size_t)i4*4] = acc;
    }
    if (tid < 128) {
        int i4 = tid;
        f4 acc = {0.f,0.f,0.f,0.f};
        #pragma unroll
        for (int k = 0; k < 8; ++k) acc += al8[k] * B4[k*128 + i4];
        *(f4*)&s.Bm[i4>>1][(i4&1)*4] = acc;
        if (EMIT) *(f4*)&out[O_BSEQ + bt*512 + (size_t)i4*4] = acc;
    }
    #pragma unroll
    for (int e = 0; e < 2; ++e) {
        int i4 = tid + e*256;
        f4 acc = {0.f,0.f,0.f,0.f};
        #pragma unroll
        for (int k = 0; k < 8; ++k) acc += al8[k] * C4[k*512 + i4];
        *(f4*)&s.C[i4>>4][(i4&15)*4] = acc;
    }
}

__global__ void __launch_bounds__(NT, 1)
kalman_seq(const float* __restrict__ a_seq, const float* __restrict__ h_obs,
           const float* __restrict__ u_seq, const float* __restrict__ mask,
           const float* __restrict__ A_mats, const float* __restrict__ B_mats,
           const float* __restrict__ C_mats, const float* __restrict__ a_0,
           const float* __restrict__ P_0, const float* __restrict__ Q,
           const float* __restrict__ R, const float* __restrict__ W_ih,
           const float* __restrict__ W_hh, const float* __restrict__ b_ih,
           const float* __restrict__ b_hh, const float* __restrict__ W_out,
           const float* __restrict__ b_out, float* __restrict__ out)
{
    __shared__ SMem s;
    const int b = blockIdx.x;
    const int tid = threadIdx.x;
    const int r4 = (tid >> 4) << 2;   // 4-row base (64-row tiles)
    const int c4 = (tid & 15) << 2;   // 4-col base (64-col tiles)

    // flat lower-triangle (incl diag) index map for wave-0 LDL (528 entries, 9 passes x 64 lanes)
    int ri[9], rj[9];
    if (tid < 64) {
        #pragma unroll
        for (int p = 0; p < 9; ++p) {
            int f = p*64 + tid;
            if (f < 528) {
                int i = (int)((__builtin_sqrtf(8.f*(float)f + 1.f) - 1.f) * 0.5f);
                while ((i+1)*(i+2)/2 <= f) ++i;
                while (i*(i+1)/2 > f) --i;
                ri[p] = i; rj[p] = f - i*(i+1)/2;
            } else { ri[p] = 0; rj[p] = 0; }
        }
    }

    // ---------------- init ----------------
    for (int idx = tid; idx < DZc*DZc; idx += NT) {
        s.P[idx >> 6][idx & 63]  = P_0[idx];
        s.Qm[idx >> 6][idx & 63] = Q[idx];
    }
    for (int idx = tid; idx < DAc*DAc; idx += NT) s.Rm[idx >> 5][idx & 31] = R[idx];
    if (tid < HG) s.h[tid] = 0.f;
    if (tid < DZc) s.z[tid] = 0.f;
    if (tid < DAc)                 s.x[tid] = a_0[tid];
    else if (tid < DAc + DOBSc)    s.x[tid] = h_obs[b*DOBSc + (tid - DAc)];
    else if (tid < DINc)           s.x[tid] = u_seq[(size_t)b*BT*DUc + (tid - DAc - DOBSc)];
    __syncthreads();

    // init alpha_net (h = 0 -> gh = b_hh exactly)
    for (int g = tid; g < 3*HG; g += NT) {
        float acc = b_ih[g];
        const float* wr = W_ih + (size_t)g * DINc;
        #pragma unroll
        for (int d = 0; d < DINc; ++d) acc += wr[d] * s.x[d];
        s.gi[g] = acc;
        s.gh[g] = b_hh[g];
    }
    __syncthreads();
    if (tid < HG) {
        float r  = 1.f / (1.f + expf(-(s.gi[tid] + s.gh[tid])));
        float zg = 1.f / (1.f + expf(-(s.gi[HG+tid] + s.gh[HG+tid])));
        float n  = tanhf(s.gi[2*HG+tid] + r * s.gh[2*HG+tid]);
        s.h[tid] = (1.f - zg) * n;    // h_old = 0
    }
    __syncthreads();
    if (tid < KMIX) {
        float acc = b_out[tid];
        const float* wr = W_out + tid * HG;
        #pragma unroll 8
        for (int d = 0; d < HG; ++d) acc += wr[d] * s.h[d];
        s.gip[tid] = acc;   // stash logits
    }
    __syncthreads();
    {
        float lg[8];
        #pragma unroll
        for (int k = 0; k < 8; ++k) lg[k] = s.gip[k];
        float mx = lg[0];
        #pragma unroll
        for (int k = 1; k < 8; ++k) mx = fmaxf(mx, lg[k]);
        float al[8]; float sum = 0.f;
        #pragma unroll
        for (int k = 0; k < 8; ++k) { al[k] = expf(lg[k] - mx); sum += al[k]; }
        float rs = 1.f / sum;
        #pragma unroll
        for (int k = 0; k < 8; ++k) al[k] *= rs;
        mix_apply<false>(s, tid, 0, al, A_mats, B_mats, C_mats, out);
    }
    __syncthreads();

    for (int t = 0; t < BT; ++t) {
        const size_t bt = (size_t)b * BT + t;

        // ---- P0: zp = A z + B u (u from global); load ak (also speculative x), u, mk ----
        if (tid < DZc) {
            float acc = 0.f;
            #pragma unroll
            for (int k4 = 0; k4 < 16; ++k4)
                acc += dot4(*(const f4*)&s.A[tid][k4*4], *(const f4*)&s.z[k4*4]);
            const float* up = u_seq + bt*DUc;
            #pragma unroll
            for (int q = 0; q < DUc; ++q) acc += s.Bm[tid][q] * up[q];
            s.zp[tid] = acc;
        } else if (tid < 96) {
            float av = a_seq[bt*DAc + (tid-64)];
            s.ak[tid-64] = av;
            s.x[tid-64] = av;                 // speculative a_k_hat (exact when mk==1)
        } else if (tid < 104) {
            float uv = u_seq[bt*DUc + (tid-96)];
            s.u[tid-96] = uv; s.x[48 + (tid-96)] = uv;
        } else if (tid == 104) {
            s.mk = mask[bt];
        }
        __syncthreads();
        const float mkv = s.mk;
        const bool mk1 = (mkv == 1.0f);

        // ---- P1: CP = C @ P (1 row x 8 cols per thread) ; rvec ----
        {
            const int r = tid >> 3;
            const int c8 = (tid & 7) * 8;
            f4 acc0 = {0.f,0.f,0.f,0.f}, acc1 = {0.f,0.f,0.f,0.f};
            #pragma unroll
            for (int k4 = 0; k4 < 16; ++k4) {
                f4 cr = *(const f4*)&s.C[r][k4*4];
                #pragma unroll
                for (int kk = 0; kk < 4; ++kk) {
                    float cv = cr[kk];
                    acc0 += cv * *(const f4*)&s.P[k4*4+kk][c8];
                    acc1 += cv * *(const f4*)&s.P[k4*4+kk][c8+4];
                }
            }
            *(f4*)&s.CP[r][c8]   = acc0;
            *(f4*)&s.CP[r][c8+4] = acc1;
        }
        if (tid < DAc) {
            float acc = 0.f;
            #pragma unroll
            for (int k4 = 0; k4 < 16; ++k4)
                acc += dot4(*(const f4*)&s.C[tid][k4*4], *(const f4*)&s.zp[k4*4]);
            s.rvec[tid] = s.ak[tid] - acc;
        }
        __syncthreads();

        // ---- P2: S = CP C^T + R (1x4 tiles) ; coalesced f4 emit ----
        {
            const int r = tid >> 3;
            const int cb = (tid & 7) * 4;
            f4 acc = {0.f,0.f,0.f,0.f};
            #pragma unroll
            for (int k4 = 0; k4 < 16; ++k4) {
                f4 a = *(const f4*)&s.CP[r][k4*4];
                #pragma unroll
                for (int j = 0; j < 4; ++j)
                    acc[j] += dot4(a, *(const f4*)&s.C[cb+j][k4*4]);
            }
            f4 rm = {s.Rm[r][cb], s.Rm[r][cb+1], s.Rm[r][cb+2], s.Rm[r][cb+3]};
            f4 v = acc + rm;
            s.S[r][cb] = v[0]; s.S[r][cb+1] = v[1]; s.S[r][cb+2] = v[2]; s.S[r][cb+3] = v[3];
            *(f4*)&out[O_SPRED + bt*1024 + (size_t)r*32 + cb] = v;
        }
        __syncthreads();

        // ---- P3: wave0: LDL^T + solves (wave-sync, no barriers)
        //          waves1-3: GRU gh (full) + gi (speculative full) + gip (cols>=32) ----
        if (tid < 64) {
            const int lane = tid;
            // LDL^T in place: raw columns kept; D[k] on diag
            #pragma unroll
            for (int k = 0; k < DAc; ++k) {
                float dv = 1.0f / s.S[k][k];
                if (lane == 0) s.dinv[k] = dv;
                #pragma unroll
                for (int p = 0; p < 9; ++p) {
                    int i = ri[p], j = rj[p];
                    if ((p*64 + lane < 528) && (j > k))
                        s.S[i][j] -= s.S[i][k] * s.S[j][k] * dv;
                }
            }
            float dv[32];
            #pragma unroll
            for (int k = 0; k < 32; ++k) dv[k] = s.dinv[k];
            // solve S x = CP[:, lane]  via L D L^T (unit L, raw cols scaled on the fly)
            float v[32], e[32];
            #pragma unroll
            for (int r = 0; r < 32; ++r) v[r] = s.CP[r][lane];
            e[0] = dv[0] * v[0];
            #pragma unroll
            for (int r = 1; r < 32; ++r) {
                float acc = v[r];
                #pragma unroll
                for (int k = 0; k < r; ++k) acc -= s.S[r][k] * e[k];
                v[r] = acc;
                e[r] = dv[r] * acc;
            }
            #pragma unroll
            for (int r = 0; r < 32; ++r) v[r] = e[r];   // D^{-1} L^{-1} b
            #pragma unroll
            for (int r = 30; r >= 0; --r) {
                float acc = 0.f;
                #pragma unroll
                for (int k = r+1; k < 32; ++k) acc += s.S[k][r] * v[k];
                v[r] -= dv[r] * acc;
            }
            float accz = 0.f;
            #pragma unroll
            for (int r = 0; r < 32; ++r) {
                s.Xm[r][lane] = v[r];
                accz += v[r] * s.rvec[r];
            }
            s.zn[lane] = s.zp[lane] + mkv * accz;
        } else {
            const int grp = (tid - 64) >> 5;        // 0..5
            const int lane = tid & 31;
            f4 hv = *(const f4*)&s.h[lane*4];
            f4 xv = {0.f,0.f,0.f,0.f};
            if (lane < 14) xv = *(const f4*)&s.x[lane*4];
            for (int g = grp; g < 3*HG; g += 6) {
                f4 wh = *(const f4*)(W_hh + (size_t)g*HG + lane*4);
                float ah = dot4(hv, wh);
                float ai = 0.f;
                if (lane < 14) ai = dot4(xv, *(const f4*)(W_ih + (size_t)g*DINc + lane*4));
                float ap = (lane >= 8) ? ai : 0.f;   // contribution of cols >= 32
                #pragma unroll
                for (int m = 16; m >= 1; m >>= 1) {
                    ah += __shfl_xor(ah, m);
                    ai += __shfl_xor(ai, m);
                    ap += __shfl_xor(ap, m);
                }
                if (lane == 0) {
                    float bi = b_ih[g];
                    s.gh[g] = ah + b_hh[g];
                    s.gi[g] = ai + bi;
                    s.gip[g] = ap + bi;
                }
            }
        }
        __syncthreads();

        // ---- P4: G = X^T CP -> Wk ; z_filt emits ----
        {
            float acc[4][4] = {{0.f,0.f,0.f,0.f},{0.f,0.f,0.f,0.f},{0.f,0.f,0.f,0.f},{0.f,0.f,0.f,0.f}};
            #pragma unroll 4
            for (int l = 0; l < DAc; ++l) {
                f4 bv = *(const f4*)&s.CP[l][c4];
                float a0 = s.Xm[l][r4], a1 = s.Xm[l][r4+1], a2 = s.Xm[l][r4+2], a3 = s.Xm[l][r4+3];
                #pragma unroll
                for (int j = 0; j < 4; ++j) {
                    acc[0][j] += a0*bv[j]; acc[1][j] += a1*bv[j];
                    acc[2][j] += a2*bv[j]; acc[3][j] += a3*bv[j];
                }
            }
            #pragma unroll
            for (int i = 0; i < 4; ++i) {
                f4 v = {acc[i][0],acc[i][1],acc[i][2],acc[i][3]};
                *(f4*)&s.Wk[r4+i][c4] = v;
            }
        }
        if (tid < DZc) {
            float v = s.zn[tid];
            out[O_ZFILT + bt*DZc + tid] = v;
            out[O_ZMEAN + bt*DZc + tid] = v;
            s.z[tid] = v;
        }
        __syncthreads();

        // ---- P5: P_filt = P + (mk^2-2mk) sym(G) + emit ; a_filt ; x ; C_seq ; (fast: h) ----
        {
            const float coef = (mkv*mkv - 2.f*mkv) * 0.5f;
            f4 gcol[4];
            #pragma unroll
            for (int j = 0; j < 4; ++j) gcol[j] = *(const f4*)&s.Wk[c4+j][r4];
            #pragma unroll
            for (int i = 0; i < 4; ++i) {
                f4 grow = *(const f4*)&s.Wk[r4+i][c4];
                f4 p = *(const f4*)&s.P[r4+i][c4];
                f4 v;
                #pragma unroll
                for (int j = 0; j < 4; ++j)
                    v[j] = p[j] + coef * (grow[j] + gcol[j][i]);
                *(f4*)&s.P[r4+i][c4] = v;
                *(f4*)&out[O_PFILT + bt*4096 + (size_t)(r4+i)*64 + c4] = v;
            }
        }
        if (tid < DAc) {
            float acc = 0.f;
            #pragma unroll
            for (int k4 = 0; k4 < 16; ++k4)
                acc += dot4(*(const f4*)&s.C[tid][k4*4], *(const f4*)&s.zn[k4*4]);
            out[O_AFILT + bt*DAc + tid] = acc;
            s.x[tid] = mkv * s.ak[tid] + (1.f - mkv) * acc;   // a_k_hat
        }
        #pragma unroll
        for (int e = 0; e < 2; ++e) {
            int i4 = tid + e*256;
            *(f4*)&out[O_CSEQ + bt*2048 + (size_t)i4*4] = *(const f4*)&s.C[i4>>4][(i4&15)*4];
        }
        if (mk1 && tid < HG) {
            float gi0 = s.gi[tid], gi1 = s.gi[HG+tid], gi2 = s.gi[2*HG+tid];
            float gh0 = s.gh[tid], gh1 = s.gh[HG+tid], gh2 = s.gh[2*HG+tid];
            float hold = s.h[tid];
            float r  = 1.f / (1.f + expf(-(gi0 + gh0)));
            float zg = 1.f / (1.f + expf(-(gi1 + gh1)));
            float n  = tanhf(gi2 + r * gh2);
            s.h[tid] = (1.f - zg) * n + zg * hold;
        }
        __syncthreads();

        if (!mk1) {
            // fix gi with the true a_k_hat (cols 0..31), then h-update
            {
                const int grpf = tid >> 5;
                const int lane = tid & 31;
                float xl = s.x[lane];
                for (int g = grpf; g < 3*HG; g += 8) {
                    float acc = W_ih[(size_t)g*DINc + lane] * xl;
                    #pragma unroll
                    for (int m = 16; m >= 1; m >>= 1) acc += __shfl_xor(acc, m);
                    if (lane == 0) s.gi[g] = s.gip[g] + acc;
                }
            }
            __syncthreads();
            if (tid < HG) {
                float gi0 = s.gi[tid], gi1 = s.gi[HG+tid], gi2 = s.gi[2*HG+tid];
                float gh0 = s.gh[tid], gh1 = s.gh[HG+tid], gh2 = s.gh[2*HG+tid];
                float hold = s.h[tid];
                float r  = 1.f / (1.f + expf(-(gi0 + gh0)));
                float zg = 1.f / (1.f + expf(-(gi1 + gh1)));
                float n  = tanhf(gi2 + r * gh2);
                s.h[tid] = (1.f - zg) * n + zg * hold;
            }
            __syncthreads();
        }

        // ---- P6: logits (per-wave replicated) + softmax + mix + emits ----
        {
            const int lane = tid & 63;
            const int g8 = lane >> 3;
            const int cb = (lane & 7) * 16;
            float acc = 0.f;
            #pragma unroll
            for (int q = 0; q < 4; ++q)
                acc += dot4(*(const f4*)&s.h[cb + q*4],
                            *(const f4*)(W_out + (size_t)g8*HG + cb + q*4));
            acc += __shfl_xor(acc, 1); acc += __shfl_xor(acc, 2); acc += __shfl_xor(acc, 4);
            float lg[8];
            #pragma unroll
            for (int g = 0; g < 8; ++g) lg[g] = __shfl(acc, g*8) + b_out[g];
            float mx = lg[0];
            #pragma unroll
            for (int k = 1; k < 8; ++k) mx = fmaxf(mx, lg[k]);
            float al[8]; float sum = 0.f;
            #pragma unroll
            for (int k = 0; k < 8; ++k) { al[k] = expf(lg[k] - mx); sum += al[k]; }
            float rs = 1.f / sum;
            #pragma unroll
            for (int k = 0; k < 8; ++k) al[k] *= rs;
            if (tid == 0) {
                #pragma unroll
                for (int k = 0; k < 8; ++k) out[O_ALPHA + bt*8 + k] = al[k];
            }
            mix_apply<true>(s, tid, bt, al, A_mats, B_mats, C_mats, out);
        }
        __syncthreads();

        // ---- P7: Wk = A_new @ P_filt ; z_pred ----
        if (tid < DZc) {
            float acc = 0.f;
            #pragma unroll
            for (int k4 = 0; k4 < 16; ++k4)
                acc += dot4(*(const f4*)&s.A[tid][k4*4], *(const f4*)&s.z[k4*4]);
            acc += dot4(*(const f4*)&s.Bm[tid][0], *(const f4*)&s.u[0]);
            acc += dot4(*(const f4*)&s.Bm[tid][4], *(const f4*)&s.u[4]);
            s.zp[tid] = acc;
            out[O_ZPRED + bt*DZc + tid] = acc;
        }
        {
            float acc[4][4] = {{0.f,0.f,0.f,0.f},{0.f,0.f,0.f,0.f},{0.f,0.f,0.f,0.f},{0.f,0.f,0.f,0.f}};
            #pragma unroll
            for (int k4 = 0; k4 < 16; ++k4) {
                f4 ar[4];
                #pragma unroll
                for (int i = 0; i < 4; ++i) ar[i] = *(const f4*)&s.A[r4+i][k4*4];
                #pragma unroll
                for (int kk = 0; kk < 4; ++kk) {
                    f4 bv = *(const f4*)&s.P[k4*4+kk][c4];
                    #pragma unroll
                    for (int i = 0; i < 4; ++i) {
                        float av = ar[i][kk];
                        #pragma unroll
                        for (int j = 0; j < 4; ++j) acc[i][j] += av * bv[j];
                    }
                }
            }
            #pragma unroll
            for (int i = 0; i < 4; ++i) {
                f4 v = {acc[i][0],acc[i][1],acc[i][2],acc[i][3]};
                *(f4*)&s.Wk[r4+i][c4] = v;
            }
        }
        __syncthreads();

        // ---- P8: P_pred = Wk @ A^T + Q -> s.P + coalesced emit (no symmetrize) ; a_pred ----
        {
            float acc[4][4] = {{0.f,0.f,0.f,0.f},{0.f,0.f,0.f,0.f},{0.f,0.f,0.f,0.f},{0.f,0.f,0.f,0.f}};
            #pragma unroll
            for (int k4 = 0; k4 < 16; ++k4) {
                f4 w0 = *(const f4*)&s.Wk[r4+0][k4*4];
                f4 w1 = *(const f4*)&s.Wk[r4+1][k4*4];
                f4 w2 = *(const f4*)&s.Wk[r4+2][k4*4];
                f4 w3 = *(const f4*)&s.Wk[r4+3][k4*4];
                #pragma unroll
                for (int j = 0; j < 4; ++j) {
                    f4 a = *(const f4*)&s.A[c4+j][k4*4];
                    acc[0][j] += dot4(w0,a); acc[1][j] += dot4(w1,a);
                    acc[2][j] += dot4(w2,a); acc[3][j] += dot4(w3,a);
                }
            }
            #pragma unroll
            for (int i = 0; i < 4; ++i) {
                f4 q = *(const f4*)&s.Qm[r4+i][c4];
                f4 v = {acc[i][0]+q[0],acc[i][1]+q[1],acc[i][2]+q[2],acc[i][3]+q[3]};
                *(f4*)&s.P[r4+i][c4] = v;
                *(f4*)&out[O_PPRED + bt*4096 + (size_t)(r4+i)*64 + c4] = v;
            }
        }
        if (tid < DAc) {
            float acc = 0.f;
            #pragma unroll
            for (int k4 = 0; k4 < 16; ++k4)
                acc += dot4(*(const f4*)&s.C[tid][k4*4], *(const f4*)&s.zp[k4*4]);
            out[O_APRED + bt*DAc + tid] = acc;
        }
        __syncthreads();
    }
}

// ---- kernel 2: batched 64x64 Cholesky for z_scale_tril (off the sequential path) ----
__global__ void __launch_bounds__(64, 4)
chol_batch(float* __restrict__ out)
{
    __shared__ float M[DZc][68];
    const size_t bt = blockIdx.x;
    const int lane = threadIdx.x;
    const float* src = out + O_PFILT + bt*4096;
    #pragma unroll
    for (int e = 0; e < 16; ++e) {
        int i4 = lane + e*64;
        f4 v = *(const f4*)(src + (size_t)i4*4);
        *(f4*)&M[i4>>4][(i4&15)*4] = v;
    }
    __syncthreads();
    float row[64];
    #pragma unroll
    for (int k = 0; k < 64; ++k) row[k] = M[lane][k];
    row[lane] += 2.0e-4f;   // + 2*JITTER
    #pragma unroll
    for (int k = 0; k < 64; ++k) {
        float acc = row[k];
        #pragma unroll
        for (int m = 0; m < k; ++m) acc -= row[m] * __shfl(row[m], k);
        float d = sqrtf(__shfl(acc, k));
        float inv = 1.0f / d;
        row[k] = (lane == k) ? d : acc * inv;
    }
    #pragma unroll
    for (int k = 0; k < 64; ++k) M[lane][k] = (k <= lane) ? row[k] : 0.f;
    __syncthreads();
    float* dst = out + O_LTRIL + bt*4096;
    #pragma unroll
    for (int e = 0; e < 16; ++e) {
        int i4 = lane + e*64;
        *(f4*)(dst + (size_t)i4*4) = *(const f4*)&M[i4>>4][(i4&15)*4];
    }
}

extern "C" void kernel_launch(void* const* d_in, const int* in_sizes, int n_in,
                              void* d_out, int out_size, void* d_ws, size_t ws_size,
                              hipStream_t stream) {
    const float* a_seq  = (const float*)d_in[0];
    const float* h_obs  = (const float*)d_in[1];
    const float* u_seq  = (const float*)d_in[2];
    const float* mask   = (const float*)d_in[3];
    const float* A_mats = (const float*)d_in[4];
    const float* B_mats = (const float*)d_in[5];
    const float* C_mats = (const float*)d_in[6];
    const float* a_0    = (const float*)d_in[7];
    const float* P_0    = (const float*)d_in[8];
    const float* Q      = (const float*)d_in[9];
    const float* R      = (const float*)d_in[10];
    const float* W_ih   = (const float*)d_in[11];
    const float* W_hh   = (const float*)d_in[12];
    const float* b_ih   = (const float*)d_in[13];
    const float* b_hh   = (const float*)d_in[14];
    const float* W_out  = (const float*)d_in[15];
    const float* b_out  = (const float*)d_in[16];
    float* out = (float*)d_out;

    kalman_seq<<<dim3(BB), dim3(NT), 0, stream>>>(a_seq, h_obs, u_seq, mask,
        A_mats, B_mats, C_mats, a_0, P_0, Q, R, W_ih, W_hh, b_ih, b_hh, W_out, b_out, out);
    chol_batch<<<dim3(BB*BT), dim3(64), 0, stream>>>(out);
}

// Round 4
// 10841.122 us; speedup vs baseline: 1.4194x; 1.4194x over previous
//
#include <hip/hip_runtime.h>

typedef float f4 __attribute__((ext_vector_type(4)));

#define NT 256
#define BB 128
#define BT 100
#define DZc 64
#define DAc 32
#define DUc 8
#define KMIX 8
#define DOBSc 16
#define HG 128
#define DINc 56   // DA + DOBS + DU

// flat element offsets into d_out (return order of the reference tuple)
#define O_ZFILT   0LL
#define O_PFILT   819200LL
#define O_ZPRED   53248000LL
#define O_AFILT   54067200LL
#define O_APRED   54476800LL
#define O_PPRED   54886400LL
#define O_ALPHA   107315200LL
#define O_ASEQ    107417600LL
#define O_BSEQ    159846400LL
#define O_CSEQ    166400000LL
#define O_ZMEAN   192614400LL
#define O_LTRIL   193433600LL
#define O_SPRED   245862400LL

__device__ __forceinline__ float dot4(f4 a, f4 b) {
    return a[0]*b[0] + a[1]*b[1] + a[2]*b[2] + a[3]*b[3];
}

struct SMem {
    float P[DZc][68];     // covariance carry (P_pred -> P_filt -> P_pred)
    float A[DZc][68];     // mixed A
    float Wk[DZc][68];    // temp: G = X^T CP ; then A@P_filt
    float Qm[DZc][68];    // Q cached
    float C[DAc][68];     // mixed C
    float CP[DAc][68];    // C@P (kept raw through the solve)
    float Xm[DAc][68];    // X = S^{-1} C P
    float S[DAc][33];     // innovation cov -> LDL^T (raw cols, D on diag)
    float Rm[DAc][33];    // R cached
    float dinv[DAc];
    float Bm[DZc][8];     // mixed B
    float z[DZc], zp[DZc], zn[DZc];
    float h[HG];
    float gh[3*HG], gi[3*HG];
    float x[64];          // [a_k_hat(32) | h_obs(16) | u(8)]
    float ak[DAc], rvec[DAc];
    float u[8];
    float lg[8];
    float mk;
};

template<bool EMIT>
__device__ __forceinline__ void mix_apply(SMem& s, int tid, size_t bt, const float* al8,
    const float* __restrict__ A_mats, const float* __restrict__ B_mats,
    const float* __restrict__ C_mats, float* __restrict__ out)
{
    const f4* A4 = (const f4*)A_mats;
    const f4* B4 = (const f4*)B_mats;
    const f4* C4 = (const f4*)C_mats;
    #pragma unroll
    for (int e = 0; e < 4; ++e) {
        int i4 = tid + e*256;
        f4 acc = {0.f,0.f,0.f,0.f};
        #pragma unroll
        for (int k = 0; k < 8; ++k) acc += al8[k] * A4[k*1024 + i4];
        *(f4*)&s.A[i4>>4][(i4&15)*4] = acc;
        if (EMIT) *(f4*)&out[O_ASEQ + bt*4096 + (size_t)i4*4] = acc;
    }
    if (tid < 128) {
        int i4 = tid;
        f4 acc = {0.f,0.f,0.f,0.f};
        #pragma unroll
        for (int k = 0; k < 8; ++k) acc += al8[k] * B4[k*128 + i4];
        *(f4*)&s.Bm[i4>>1][(i4&1)*4] = acc;
        if (EMIT) *(f4*)&out[O_BSEQ + bt*512 + (size_t)i4*4] = acc;
    }
    #pragma unroll
    for (int e = 0; e < 2; ++e) {
        int i4 = tid + e*256;
        f4 acc = {0.f,0.f,0.f,0.f};
        #pragma unroll
        for (int k = 0; k < 8; ++k) acc += al8[k] * C4[k*512 + i4];
        *(f4*)&s.C[i4>>4][(i4&15)*4] = acc;
    }
}

__global__ void __launch_bounds__(NT, 1)
kalman_seq(const float* __restrict__ a_seq, const float* __restrict__ h_obs,
           const float* __restrict__ u_seq, const float* __restrict__ mask,
           const float* __restrict__ A_mats, const float* __restrict__ B_mats,
           const float* __restrict__ C_mats, const float* __restrict__ a_0,
           const float* __restrict__ P_0, const float* __restrict__ Q,
           const float* __restrict__ R, const float* __restrict__ W_ih,
           const float* __restrict__ W_hh, const float* __restrict__ b_ih,
           const float* __restrict__ b_hh, const float* __restrict__ W_out,
           const float* __restrict__ b_out, float* __restrict__ out)
{
    __shared__ SMem s;
    const int b = blockIdx.x;
    const int tid = threadIdx.x;
    const int r4 = (tid >> 4) << 2;   // 4-row base (64-row tiles)
    const int c4 = (tid & 15) << 2;   // 4-col base (64-col tiles)

    // ---------------- init ----------------
    for (int idx = tid; idx < DZc*DZc; idx += NT) {
        s.P[idx >> 6][idx & 63]  = P_0[idx];
        s.Qm[idx >> 6][idx & 63] = Q[idx];
    }
    for (int idx = tid; idx < DAc*DAc; idx += NT) s.Rm[idx >> 5][idx & 31] = R[idx];
    if (tid < HG) s.h[tid] = 0.f;
    if (tid < DZc) s.z[tid] = 0.f;
    if (tid < DAc)                 s.x[tid] = a_0[tid];
    else if (tid < DAc + DOBSc)    s.x[tid] = h_obs[b*DOBSc + (tid - DAc)];
    else if (tid < DINc)           s.x[tid] = u_seq[(size_t)b*BT*DUc + (tid - DAc - DOBSc)];
    __syncthreads();

    // init alpha_net (h = 0 -> gh = b_hh exactly)
    for (int g = tid; g < 3*HG; g += NT) {
        const float* wi = W_ih + (size_t)g * DINc;
        f4 ai = {0.f,0.f,0.f,0.f};
        #pragma unroll
        for (int q = 0; q < 14; ++q) ai += *(const f4*)(wi + q*4) * *(const f4*)&s.x[q*4];
        s.gi[g] = ai[0]+ai[1]+ai[2]+ai[3] + b_ih[g];
        s.gh[g] = b_hh[g];
    }
    __syncthreads();
    if (tid < HG) {
        float r  = 1.f / (1.f + expf(-(s.gi[tid] + s.gh[tid])));
        float zg = 1.f / (1.f + expf(-(s.gi[HG+tid] + s.gh[HG+tid])));
        float n  = tanhf(s.gi[2*HG+tid] + r * s.gh[2*HG+tid]);
        s.h[tid] = (1.f - zg) * n;    // h_old = 0
    }
    __syncthreads();
    if (tid < KMIX) {
        const float* wo = W_out + tid * HG;
        f4 acc = {0.f,0.f,0.f,0.f};
        #pragma unroll
        for (int q = 0; q < 32; ++q) acc += *(const f4*)(wo + q*4) * *(const f4*)&s.h[q*4];
        s.lg[tid] = acc[0]+acc[1]+acc[2]+acc[3] + b_out[tid];
    }
    __syncthreads();
    {
        float lg[8];
        #pragma unroll
        for (int k = 0; k < 8; ++k) lg[k] = s.lg[k];
        float mx = lg[0];
        #pragma unroll
        for (int k = 1; k < 8; ++k) mx = fmaxf(mx, lg[k]);
        float al[8]; float sum = 0.f;
        #pragma unroll
        for (int k = 0; k < 8; ++k) { al[k] = expf(lg[k] - mx); sum += al[k]; }
        float rs = 1.f / sum;
        #pragma unroll
        for (int k = 0; k < 8; ++k) al[k] *= rs;
        mix_apply<false>(s, tid, 0, al, A_mats, B_mats, C_mats, out);
    }
    __syncthreads();

    for (int t = 0; t < BT; ++t) {
        const size_t bt = (size_t)b * BT + t;

        // ---- P0: zp = A z + B u ; load ak (speculative x), u, mk ----
        if (tid < DZc) {
            float acc = 0.f;
            #pragma unroll
            for (int k4 = 0; k4 < 16; ++k4)
                acc += dot4(*(const f4*)&s.A[tid][k4*4], *(const f4*)&s.z[k4*4]);
            const float* up = u_seq + bt*DUc;
            #pragma unroll
            for (int q = 0; q < DUc; ++q) acc += s.Bm[tid][q] * up[q];
            s.zp[tid] = acc;
        } else if (tid < 96) {
            float av = a_seq[bt*DAc + (tid-64)];
            s.ak[tid-64] = av;
            s.x[tid-64] = av;                 // speculative a_k_hat (exact when mk==1)
        } else if (tid < 104) {
            float uv = u_seq[bt*DUc + (tid-96)];
            s.u[tid-96] = uv; s.x[48 + (tid-96)] = uv;
        } else if (tid == 104) {
            s.mk = mask[bt];
        }
        __syncthreads();
        const float mkv = s.mk;
        const bool mk1 = (mkv == 1.0f);

        // ---- P1: CP = C @ P (1 row x 8 cols per thread) ; rvec ----
        {
            const int r = tid >> 3;
            const int c8 = (tid & 7) * 8;
            f4 acc0 = {0.f,0.f,0.f,0.f}, acc1 = {0.f,0.f,0.f,0.f};
            #pragma unroll
            for (int k4 = 0; k4 < 16; ++k4) {
                f4 cr = *(const f4*)&s.C[r][k4*4];
                #pragma unroll
                for (int kk = 0; kk < 4; ++kk) {
                    float cv = cr[kk];
                    acc0 += cv * *(const f4*)&s.P[k4*4+kk][c8];
                    acc1 += cv * *(const f4*)&s.P[k4*4+kk][c8+4];
                }
            }
            *(f4*)&s.CP[r][c8]   = acc0;
            *(f4*)&s.CP[r][c8+4] = acc1;
        }
        if (tid < DAc) {
            float acc = 0.f;
            #pragma unroll
            for (int k4 = 0; k4 < 16; ++k4)
                acc += dot4(*(const f4*)&s.C[tid][k4*4], *(const f4*)&s.zp[k4*4]);
            s.rvec[tid] = s.ak[tid] - acc;
        }
        __syncthreads();

        // ---- P2: S = CP C^T + R (1x4 tiles) ; coalesced f4 emit ----
        {
            const int r = tid >> 3;
            const int cb = (tid & 7) * 4;
            f4 acc = {0.f,0.f,0.f,0.f};
            #pragma unroll
            for (int k4 = 0; k4 < 16; ++k4) {
                f4 a = *(const f4*)&s.CP[r][k4*4];
                #pragma unroll
                for (int j = 0; j < 4; ++j)
                    acc[j] += dot4(a, *(const f4*)&s.C[cb+j][k4*4]);
            }
            f4 rm = {s.Rm[r][cb], s.Rm[r][cb+1], s.Rm[r][cb+2], s.Rm[r][cb+3]};
            f4 v = acc + rm;
            s.S[r][cb] = v[0]; s.S[r][cb+1] = v[1]; s.S[r][cb+2] = v[2]; s.S[r][cb+3] = v[3];
            *(f4*)&out[O_SPRED + bt*1024 + (size_t)r*32 + cb] = v;
        }
        __syncthreads();

        // ---- P3: wave0: LDL^T + solves (LDS, wave-sync via threadfence, no barriers)
        //          waves1-3: GRU gates, thread-per-gate (no shuffles) ----
        if (tid < 64) {
            const int lane = tid;
            const int l = lane & 31, par = lane >> 5;
            // LDL^T, right-looking, lane-per-row, 2 lanes/row parity split.
            for (int k = 0; k < 31; ++k) {
                __threadfence_block();               // step k-1 writes visible
                float dv = 1.0f / s.S[k][k];
                if (lane == k) s.dinv[k] = dv;
                if (l > k) {
                    float f = s.S[l][k] * dv;
                    for (int j = k + 1 + par; j <= l; j += 2)
                        s.S[l][j] -= f * s.S[j][k];
                }
            }
            __threadfence_block();
            if (lane == 31) s.dinv[31] = 1.0f / s.S[31][31];
            __threadfence_block();
            // Solve S x = CP[:, lane] via L D L^T (unit L with raw cols: L[i][k]=S[i][k]*dinv[k])
            float v[32];
            #pragma unroll
            for (int r = 0; r < 32; ++r) v[r] = s.CP[r][lane];
            #pragma unroll
            for (int r = 0; r < 32; ++r) {
                float acc = v[r];
                #pragma unroll
                for (int k = 0; k < r; ++k) acc -= s.S[r][k] * v[k];
                v[r] = s.dinv[r] * acc;              // v = D^{-1} L^{-1} b
            }
            #pragma unroll
            for (int r = 30; r >= 0; --r) {
                float acc = 0.f;
                #pragma unroll
                for (int k = r+1; k < 32; ++k) acc += s.S[k][r] * v[k];
                v[r] -= s.dinv[r] * acc;
            }
            float accz = 0.f;
            #pragma unroll
            for (int r = 0; r < 32; ++r) {
                s.Xm[r][lane] = v[r];
                accz += v[r] * s.rvec[r];
            }
            s.zn[lane] = s.zp[lane] + mkv * accz;
        } else {
            // 192 threads, 384 gates: speculative gi (x with a_k) + gh
            for (int g = tid - 64; g < 3*HG; g += 192) {
                const float* wi = W_ih + (size_t)g * DINc;
                const float* wh = W_hh + (size_t)g * HG;
                f4 ai = {0.f,0.f,0.f,0.f}, ah = {0.f,0.f,0.f,0.f};
                #pragma unroll
                for (int q = 0; q < 14; ++q) ai += *(const f4*)(wi + q*4) * *(const f4*)&s.x[q*4];
                #pragma unroll
                for (int q = 0; q < 32; ++q) ah += *(const f4*)(wh + q*4) * *(const f4*)&s.h[q*4];
                s.gi[g] = ai[0]+ai[1]+ai[2]+ai[3] + b_ih[g];
                s.gh[g] = ah[0]+ah[1]+ah[2]+ah[3] + b_hh[g];
            }
        }
        __syncthreads();

        // ---- P4: G = X^T CP -> Wk ; z_filt emits ----
        {
            float acc[4][4] = {{0.f,0.f,0.f,0.f},{0.f,0.f,0.f,0.f},{0.f,0.f,0.f,0.f},{0.f,0.f,0.f,0.f}};
            #pragma unroll 4
            for (int l = 0; l < DAc; ++l) {
                f4 bv = *(const f4*)&s.CP[l][c4];
                float a0 = s.Xm[l][r4], a1 = s.Xm[l][r4+1], a2 = s.Xm[l][r4+2], a3 = s.Xm[l][r4+3];
                #pragma unroll
                for (int j = 0; j < 4; ++j) {
                    acc[0][j] += a0*bv[j]; acc[1][j] += a1*bv[j];
                    acc[2][j] += a2*bv[j]; acc[3][j] += a3*bv[j];
                }
            }
            #pragma unroll
            for (int i = 0; i < 4; ++i) {
                f4 v = {acc[i][0],acc[i][1],acc[i][2],acc[i][3]};
                *(f4*)&s.Wk[r4+i][c4] = v;
            }
        }
        if (tid < DZc) {
            float v = s.zn[tid];
            out[O_ZFILT + bt*DZc + tid] = v;
            out[O_ZMEAN + bt*DZc + tid] = v;
            s.z[tid] = v;
        }
        __syncthreads();

        // ---- P5: P_filt = P + (mk^2-2mk) sym(G) + emit ; a_filt ; x ; C_seq ; (mk1: h) ----
        {
            const float coef = (mkv*mkv - 2.f*mkv) * 0.5f;
            f4 gcol[4];
            #pragma unroll
            for (int j = 0; j < 4; ++j) gcol[j] = *(const f4*)&s.Wk[c4+j][r4];
            #pragma unroll
            for (int i = 0; i < 4; ++i) {
                f4 grow = *(const f4*)&s.Wk[r4+i][c4];
                f4 p = *(const f4*)&s.P[r4+i][c4];
                f4 v;
                #pragma unroll
                for (int j = 0; j < 4; ++j)
                    v[j] = p[j] + coef * (grow[j] + gcol[j][i]);
                *(f4*)&s.P[r4+i][c4] = v;
                *(f4*)&out[O_PFILT + bt*4096 + (size_t)(r4+i)*64 + c4] = v;
            }
        }
        if (tid < DAc) {
            float acc = 0.f;
            #pragma unroll
            for (int k4 = 0; k4 < 16; ++k4)
                acc += dot4(*(const f4*)&s.C[tid][k4*4], *(const f4*)&s.zn[k4*4]);
            out[O_AFILT + bt*DAc + tid] = acc;
            s.x[tid] = mkv * s.ak[tid] + (1.f - mkv) * acc;   // a_k_hat (true)
        }
        #pragma unroll
        for (int e = 0; e < 2; ++e) {
            int i4 = tid + e*256;
            *(f4*)&out[O_CSEQ + bt*2048 + (size_t)i4*4] = *(const f4*)&s.C[i4>>4][(i4&15)*4];
        }
        if (mk1 && tid < HG) {
            float gi0 = s.gi[tid], gi1 = s.gi[HG+tid], gi2 = s.gi[2*HG+tid];
            float gh0 = s.gh[tid], gh1 = s.gh[HG+tid], gh2 = s.gh[2*HG+tid];
            float hold = s.h[tid];
            float r  = 1.f / (1.f + expf(-(gi0 + gh0)));
            float zg = 1.f / (1.f + expf(-(gi1 + gh1)));
            float n  = tanhf(gi2 + r * gh2);
            s.h[tid] = (1.f - zg) * n + zg * hold;
        }
        __syncthreads();

        if (!mk1) {
            // recompute gi with the true a_k_hat, then h-update
            for (int g = tid; g < 3*HG; g += NT) {
                const float* wi = W_ih + (size_t)g * DINc;
                f4 ai = {0.f,0.f,0.f,0.f};
                #pragma unroll
                for (int q = 0; q < 14; ++q) ai += *(const f4*)(wi + q*4) * *(const f4*)&s.x[q*4];
                s.gi[g] = ai[0]+ai[1]+ai[2]+ai[3] + b_ih[g];
            }
            __syncthreads();
            if (tid < HG) {
                float gi0 = s.gi[tid], gi1 = s.gi[HG+tid], gi2 = s.gi[2*HG+tid];
                float gh0 = s.gh[tid], gh1 = s.gh[HG+tid], gh2 = s.gh[2*HG+tid];
                float hold = s.h[tid];
                float r  = 1.f / (1.f + expf(-(gi0 + gh0)));
                float zg = 1.f / (1.f + expf(-(gi1 + gh1)));
                float n  = tanhf(gi2 + r * gh2);
                s.h[tid] = (1.f - zg) * n + zg * hold;
            }
            __syncthreads();
        }

        // ---- P6a: logits (8 plain dots, no shuffles) ----
        if (tid < KMIX) {
            const float* wo = W_out + tid * HG;
            f4 acc = {0.f,0.f,0.f,0.f};
            #pragma unroll
            for (int q = 0; q < 32; ++q) acc += *(const f4*)(wo + q*4) * *(const f4*)&s.h[q*4];
            s.lg[tid] = acc[0]+acc[1]+acc[2]+acc[3] + b_out[tid];
        }
        __syncthreads();

        // ---- P6b: softmax (replicated) + mix + emits ----
        {
            float lg[8];
            #pragma unroll
            for (int k = 0; k < 8; ++k) lg[k] = s.lg[k];
            float mx = lg[0];
            #pragma unroll
            for (int k = 1; k < 8; ++k) mx = fmaxf(mx, lg[k]);
            float al[8]; float sum = 0.f;
            #pragma unroll
            for (int k = 0; k < 8; ++k) { al[k] = expf(lg[k] - mx); sum += al[k]; }
            float rs = 1.f / sum;
            #pragma unroll
            for (int k = 0; k < 8; ++k) al[k] *= rs;
            if (tid < 8) out[O_ALPHA + bt*8 + tid] = al[tid];
            mix_apply<true>(s, tid, bt, al, A_mats, B_mats, C_mats, out);
        }
        __syncthreads();

        // ---- P7: Wk = A_new @ P_filt ; z_pred ----
        if (tid < DZc) {
            float acc = 0.f;
            #pragma unroll
            for (int k4 = 0; k4 < 16; ++k4)
                acc += dot4(*(const f4*)&s.A[tid][k4*4], *(const f4*)&s.z[k4*4]);
            acc += dot4(*(const f4*)&s.Bm[tid][0], *(const f4*)&s.u[0]);
            acc += dot4(*(const f4*)&s.Bm[tid][4], *(const f4*)&s.u[4]);
            s.zp[tid] = acc;
            out[O_ZPRED + bt*DZc + tid] = acc;
        }
        {
            float acc[4][4] = {{0.f,0.f,0.f,0.f},{0.f,0.f,0.f,0.f},{0.f,0.f,0.f,0.f},{0.f,0.f,0.f,0.f}};
            #pragma unroll
            for (int k4 = 0; k4 < 16; ++k4) {
                f4 ar[4];
                #pragma unroll
                for (int i = 0; i < 4; ++i) ar[i] = *(const f4*)&s.A[r4+i][k4*4];
                #pragma unroll
                for (int kk = 0; kk < 4; ++kk) {
                    f4 bv = *(const f4*)&s.P[k4*4+kk][c4];
                    #pragma unroll
                    for (int i = 0; i < 4; ++i) {
                        float av = ar[i][kk];
                        #pragma unroll
                        for (int j = 0; j < 4; ++j) acc[i][j] += av * bv[j];
                    }
                }
            }
            #pragma unroll
            for (int i = 0; i < 4; ++i) {
                f4 v = {acc[i][0],acc[i][1],acc[i][2],acc[i][3]};
                *(f4*)&s.Wk[r4+i][c4] = v;
            }
        }
        __syncthreads();

        // ---- P8: P_pred = Wk @ A^T + Q -> s.P + coalesced emit ; a_pred ----
        {
            float acc[4][4] = {{0.f,0.f,0.f,0.f},{0.f,0.f,0.f,0.f},{0.f,0.f,0.f,0.f},{0.f,0.f,0.f,0.f}};
            #pragma unroll
            for (int k4 = 0; k4 < 16; ++k4) {
                f4 w0 = *(const f4*)&s.Wk[r4+0][k4*4];
                f4 w1 = *(const f4*)&s.Wk[r4+1][k4*4];
                f4 w2 = *(const f4*)&s.Wk[r4+2][k4*4];
                f4 w3 = *(const f4*)&s.Wk[r4+3][k4*4];
                #pragma unroll
                for (int j = 0; j < 4; ++j) {
                    f4 a = *(const f4*)&s.A[c4+j][k4*4];
                    acc[0][j] += dot4(w0,a); acc[1][j] += dot4(w1,a);
                    acc[2][j] += dot4(w2,a); acc[3][j] += dot4(w3,a);
                }
            }
            #pragma unroll
            for (int i = 0; i < 4; ++i) {
                f4 q = *(const f4*)&s.Qm[r4+i][c4];
                f4 v = {acc[i][0]+q[0],acc[i][1]+q[1],acc[i][2]+q[2],acc[i][3]+q[3]};
                *(f4*)&s.P[r4+i][c4] = v;
                *(f4*)&out[O_PPRED + bt*4096 + (size_t)(r4+i)*64 + c4] = v;
            }
        }
        if (tid < DAc) {
            float acc = 0.f;
            #pragma unroll
            for (int k4 = 0; k4 < 16; ++k4)
                acc += dot4(*(const f4*)&s.C[tid][k4*4], *(const f4*)&s.zp[k4*4]);
            out[O_APRED + bt*DAc + tid] = acc;
        }
        __syncthreads();
    }
}

// ---- kernel 2: batched 64x64 Cholesky for z_scale_tril (off the sequential path) ----
__global__ void __launch_bounds__(64, 4)
chol_batch(float* __restrict__ out)
{
    __shared__ float M[DZc][68];
    const size_t bt = blockIdx.x;
    const int lane = threadIdx.x;
    const float* src = out + O_PFILT + bt*4096;
    #pragma unroll
    for (int e = 0; e < 16; ++e) {
        int i4 = lane + e*64;
        f4 v = *(const f4*)(src + (size_t)i4*4);
        *(f4*)&M[i4>>4][(i4&15)*4] = v;
    }
    __syncthreads();
    float row[64];
    #pragma unroll
    for (int k = 0; k < 64; ++k) row[k] = M[lane][k];
    row[lane] += 2.0e-4f;   // + 2*JITTER
    #pragma unroll
    for (int k = 0; k < 64; ++k) {
        float acc = row[k];
        #pragma unroll
        for (int m = 0; m < k; ++m) acc -= row[m] * __shfl(row[m], k);
        float d = sqrtf(__shfl(acc, k));
        float inv = 1.0f / d;
        row[k] = (lane == k) ? d : acc * inv;
    }
    #pragma unroll
    for (int k = 0; k < 64; ++k) M[lane][k] = (k <= lane) ? row[k] : 0.f;
    __syncthreads();
    float* dst = out + O_LTRIL + bt*4096;
    #pragma unroll
    for (int e = 0; e < 16; ++e) {
        int i4 = lane + e*64;
        *(f4*)(dst + (size_t)i4*4) = *(const f4*)&M[i4>>4][(i4&15)*4];
    }
}

extern "C" void kernel_launch(void* const* d_in, const int* in_sizes, int n_in,
                              void* d_out, int out_size, void* d_ws, size_t ws_size,
                              hipStream_t stream) {
    const float* a_seq  = (const float*)d_in[0];
    const float* h_obs  = (const float*)d_in[1];
    const float* u_seq  = (const float*)d_in[2];
    const float* mask   = (const float*)d_in[3];
    const float* A_mats = (const float*)d_in[4];
    const float* B_mats = (const float*)d_in[5];
    const float* C_mats = (const float*)d_in[6];
    const float* a_0    = (const float*)d_in[7];
    const float* P_0    = (const float*)d_in[8];
    const float* Q      = (const float*)d_in[9];
    const float* R      = (const float*)d_in[10];
    const float* W_ih   = (const float*)d_in[11];
    const float* W_hh   = (const float*)d_in[12];
    const float* b_ih   = (const float*)d_in[13];
    const float* b_hh   = (const float*)d_in[14];
    const float* W_out  = (const float*)d_in[15];
    const float* b_out  = (const float*)d_in[16];
    float* out = (float*)d_out;

    kalman_seq<<<dim3(BB), dim3(NT), 0, stream>>>(a_seq, h_obs, u_seq, mask,
        A_mats, B_mats, C_mats, a_0, P_0, Q, R, W_ih, W_hh, b_ih, b_hh, W_out, b_out, out);
    chol_batch<<<dim3(BB*BT), dim3(64), 0, stream>>>(out);
}

// Round 5
// 9667.058 us; speedup vs baseline: 1.5918x; 1.1214x over previous
//
#include <hip/hip_runtime.h>

typedef float f4 __attribute__((ext_vector_type(4)));

#define NT 256
#define BB 128
#define BT 100
#define DZc 64
#define DAc 32
#define DUc 8
#define KMIX 8
#define DOBSc 16
#define HG 128
#define DINc 56   // DA + DOBS + DU

// flat element offsets into d_out (return order of the reference tuple)
#define O_ZFILT   0LL
#define O_PFILT   819200LL
#define O_ZPRED   53248000LL
#define O_AFILT   54067200LL
#define O_APRED   54476800LL
#define O_PPRED   54886400LL
#define O_ALPHA   107315200LL
#define O_ASEQ    107417600LL
#define O_BSEQ    159846400LL
#define O_CSEQ    166400000LL
#define O_ZMEAN   192614400LL
#define O_LTRIL   193433600LL
#define O_SPRED   245862400LL

__device__ __forceinline__ float dot4(f4 a, f4 b) {
    return a[0]*b[0] + a[1]*b[1] + a[2]*b[2] + a[3]*b[3];
}

struct SMem {
    float P[DZc][68];     // covariance carry (P_pred -> P_filt -> P_pred)
    float A[DZc][68];     // mixed A
    float Wk[DZc][68];    // temp: G = X^T CP ; then A@P_filt
    float Qm[DZc][68];    // Q cached
    float C[DAc][68];     // mixed C
    float CP[DAc][68];    // C@P (kept raw through the solve)
    float Xm[DAc][68];    // X = S^{-1} C P (solve done in place here)
    float S[DAc][33];     // innovation cov -> LDL^T (raw cols, D on diag)
    float Rm[DAc][33];    // R cached
    float dinv[DAc];
    float Bm[DZc][8];     // mixed B
    float z[DZc], zp[DZc], zn[DZc];
    float h[HG];
    float gh[3*HG], gi[3*HG];
    float x[64];          // [a_k_hat(32) | h_obs(16) | u(8)]
    float ak[DAc], rvec[DAc];
    float u[8];
    float lg[8];
    float mk;
};

template<bool EMIT>
__device__ __forceinline__ void mix_apply(SMem& s, int tid, size_t bt, const float* al8,
    const float* __restrict__ A_mats, const float* __restrict__ B_mats,
    const float* __restrict__ C_mats, float* __restrict__ out)
{
    const f4* A4 = (const f4*)A_mats;
    const f4* B4 = (const f4*)B_mats;
    const f4* C4 = (const f4*)C_mats;
    #pragma unroll 2
    for (int e = 0; e < 4; ++e) {
        int i4 = tid + e*256;
        f4 acc = {0.f,0.f,0.f,0.f};
        #pragma unroll
        for (int k = 0; k < 8; ++k) acc += al8[k] * A4[k*1024 + i4];
        *(f4*)&s.A[i4>>4][(i4&15)*4] = acc;
        if (EMIT) *(f4*)&out[O_ASEQ + bt*4096 + (size_t)i4*4] = acc;
    }
    if (tid < 128) {
        int i4 = tid;
        f4 acc = {0.f,0.f,0.f,0.f};
        #pragma unroll
        for (int k = 0; k < 8; ++k) acc += al8[k] * B4[k*128 + i4];
        *(f4*)&s.Bm[i4>>1][(i4&1)*4] = acc;
        if (EMIT) *(f4*)&out[O_BSEQ + bt*512 + (size_t)i4*4] = acc;
    }
    #pragma unroll 1
    for (int e = 0; e < 2; ++e) {
        int i4 = tid + e*256;
        f4 acc = {0.f,0.f,0.f,0.f};
        #pragma unroll
        for (int k = 0; k < 8; ++k) acc += al8[k] * C4[k*512 + i4];
        *(f4*)&s.C[i4>>4][(i4&15)*4] = acc;
    }
}

__global__ void __launch_bounds__(NT, 1)
kalman_seq(const float* __restrict__ a_seq, const float* __restrict__ h_obs,
           const float* __restrict__ u_seq, const float* __restrict__ mask,
           const float* __restrict__ A_mats, const float* __restrict__ B_mats,
           const float* __restrict__ C_mats, const float* __restrict__ a_0,
           const float* __restrict__ P_0, const float* __restrict__ Q,
           const float* __restrict__ R, const float* __restrict__ W_ih,
           const float* __restrict__ W_hh, const float* __restrict__ b_ih,
           const float* __restrict__ b_hh, const float* __restrict__ W_out,
           const float* __restrict__ b_out, float* __restrict__ out)
{
    __shared__ SMem s;
    const int b = blockIdx.x;
    const int tid = threadIdx.x;
    const int r4 = (tid >> 4) << 2;   // 4-row base (64-row tiles)
    const int c4 = (tid & 15) << 2;   // 4-col base (64-col tiles)

    // ---------------- init ----------------
    for (int idx = tid; idx < DZc*DZc; idx += NT) {
        s.P[idx >> 6][idx & 63]  = P_0[idx];
        s.Qm[idx >> 6][idx & 63] = Q[idx];
    }
    for (int idx = tid; idx < DAc*DAc; idx += NT) s.Rm[idx >> 5][idx & 31] = R[idx];
    if (tid < HG) s.h[tid] = 0.f;
    if (tid < DZc) s.z[tid] = 0.f;
    if (tid < DAc)                 s.x[tid] = a_0[tid];
    else if (tid < DAc + DOBSc)    s.x[tid] = h_obs[b*DOBSc + (tid - DAc)];
    else if (tid < DINc)           s.x[tid] = u_seq[(size_t)b*BT*DUc + (tid - DAc - DOBSc)];
    __syncthreads();

    // init alpha_net (h = 0 -> gh = b_hh exactly)
    for (int g = tid; g < 3*HG; g += NT) {
        const float* wi = W_ih + (size_t)g * DINc;
        f4 ai = {0.f,0.f,0.f,0.f};
        #pragma unroll 7
        for (int q = 0; q < 14; ++q) ai += *(const f4*)(wi + q*4) * *(const f4*)&s.x[q*4];
        s.gi[g] = ai[0]+ai[1]+ai[2]+ai[3] + b_ih[g];
        s.gh[g] = b_hh[g];
    }
    __syncthreads();
    if (tid < HG) {
        float r  = 1.f / (1.f + expf(-(s.gi[tid] + s.gh[tid])));
        float zg = 1.f / (1.f + expf(-(s.gi[HG+tid] + s.gh[HG+tid])));
        float n  = tanhf(s.gi[2*HG+tid] + r * s.gh[2*HG+tid]);
        s.h[tid] = (1.f - zg) * n;    // h_old = 0
    }
    __syncthreads();
    if (tid < KMIX) {
        const float* wo = W_out + tid * HG;
        f4 acc = {0.f,0.f,0.f,0.f};
        #pragma unroll 8
        for (int q = 0; q < 32; ++q) acc += *(const f4*)(wo + q*4) * *(const f4*)&s.h[q*4];
        s.lg[tid] = acc[0]+acc[1]+acc[2]+acc[3] + b_out[tid];
    }
    __syncthreads();
    {
        float lg[8];
        #pragma unroll
        for (int k = 0; k < 8; ++k) lg[k] = s.lg[k];
        float mx = lg[0];
        #pragma unroll
        for (int k = 1; k < 8; ++k) mx = fmaxf(mx, lg[k]);
        float al[8]; float sum = 0.f;
        #pragma unroll
        for (int k = 0; k < 8; ++k) { al[k] = expf(lg[k] - mx); sum += al[k]; }
        float rs = 1.f / sum;
        #pragma unroll
        for (int k = 0; k < 8; ++k) al[k] *= rs;
        mix_apply<false>(s, tid, 0, al, A_mats, B_mats, C_mats, out);
    }
    __syncthreads();

    for (int t = 0; t < BT; ++t) {
        const size_t bt = (size_t)b * BT + t;

        // ---- P0: zp = A z + B u ; load ak (speculative x), u, mk ----
        if (tid < DZc) {
            float acc = 0.f;
            #pragma unroll 4
            for (int k4 = 0; k4 < 16; ++k4)
                acc += dot4(*(const f4*)&s.A[tid][k4*4], *(const f4*)&s.z[k4*4]);
            const float* up = u_seq + bt*DUc;
            #pragma unroll
            for (int q = 0; q < DUc; ++q) acc += s.Bm[tid][q] * up[q];
            s.zp[tid] = acc;
        } else if (tid < 96) {
            float av = a_seq[bt*DAc + (tid-64)];
            s.ak[tid-64] = av;
            s.x[tid-64] = av;                 // speculative a_k_hat (exact when mk==1)
        } else if (tid < 104) {
            float uv = u_seq[bt*DUc + (tid-96)];
            s.u[tid-96] = uv; s.x[48 + (tid-96)] = uv;
        } else if (tid == 104) {
            s.mk = mask[bt];
        }
        __syncthreads();
        const float mkv = s.mk;
        const bool mk1 = (mkv == 1.0f);

        // ---- P1: CP = C @ P (1 row x 8 cols per thread) ; rvec ----
        {
            const int r = tid >> 3;
            const int c8 = (tid & 7) * 8;
            f4 acc0 = {0.f,0.f,0.f,0.f}, acc1 = {0.f,0.f,0.f,0.f};
            #pragma unroll 4
            for (int k4 = 0; k4 < 16; ++k4) {
                f4 cr = *(const f4*)&s.C[r][k4*4];
                #pragma unroll
                for (int kk = 0; kk < 4; ++kk) {
                    float cv = cr[kk];
                    acc0 += cv * *(const f4*)&s.P[k4*4+kk][c8];
                    acc1 += cv * *(const f4*)&s.P[k4*4+kk][c8+4];
                }
            }
            *(f4*)&s.CP[r][c8]   = acc0;
            *(f4*)&s.CP[r][c8+4] = acc1;
        }
        if (tid < DAc) {
            float acc = 0.f;
            #pragma unroll 4
            for (int k4 = 0; k4 < 16; ++k4)
                acc += dot4(*(const f4*)&s.C[tid][k4*4], *(const f4*)&s.zp[k4*4]);
            s.rvec[tid] = s.ak[tid] - acc;
        }
        __syncthreads();

        // ---- P2: S = CP C^T + R (1x4 tiles) ; coalesced f4 emit ----
        {
            const int r = tid >> 3;
            const int cb = (tid & 7) * 4;
            f4 acc = {0.f,0.f,0.f,0.f};
            #pragma unroll 4
            for (int k4 = 0; k4 < 16; ++k4) {
                f4 a = *(const f4*)&s.CP[r][k4*4];
                #pragma unroll
                for (int j = 0; j < 4; ++j)
                    acc[j] += dot4(a, *(const f4*)&s.C[cb+j][k4*4]);
            }
            f4 rm = {s.Rm[r][cb], s.Rm[r][cb+1], s.Rm[r][cb+2], s.Rm[r][cb+3]};
            f4 v = acc + rm;
            s.S[r][cb] = v[0]; s.S[r][cb+1] = v[1]; s.S[r][cb+2] = v[2]; s.S[r][cb+3] = v[3];
            *(f4*)&out[O_SPRED + bt*1024 + (size_t)r*32 + cb] = v;
        }
        __syncthreads();

        // ---- P3: wave0: LDL^T + solves (in LDS, wave-sync, no barriers, no reg arrays)
        //          waves1-3: GRU gates, thread-per-gate (no shuffles) ----
        if (tid < 64) {
            const int lane = tid;
            const int l = lane & 31, par = lane >> 5;
            // LDL^T, right-looking, lane-per-row, 2 lanes/row parity split.
            for (int k = 0; k < 31; ++k) {
                __threadfence_block();               // step k-1 writes visible
                float dv = 1.0f / s.S[k][k];
                if (lane == k) s.dinv[k] = dv;
                if (l > k) {
                    float f = s.S[l][k] * dv;
                    for (int j = k + 1 + par; j <= l; j += 2)
                        s.S[l][j] -= f * s.S[j][k];
                }
            }
            __threadfence_block();
            if (lane == 31) s.dinv[31] = 1.0f / s.S[31][31];
            __threadfence_block();
            // Solve S x = CP[:, lane] via L D L^T, entirely in the Xm column (per-lane)
            #pragma unroll 8
            for (int r = 0; r < 32; ++r) s.Xm[r][lane] = s.CP[r][lane];
            // forward + D^{-1}: Xm[r] = dinv[r] * (Xm[r] - sum_{k<r} S[r][k]*Xm[k])
            s.Xm[0][lane] *= s.dinv[0];
            #pragma unroll 1
            for (int r = 1; r < 32; ++r) {
                float acc = s.Xm[r][lane];
                #pragma unroll 4
                for (int k = 0; k < r; ++k) acc -= s.S[r][k] * s.Xm[k][lane];
                s.Xm[r][lane] = s.dinv[r] * acc;
            }
            // backward: Xm[r] -= dinv[r] * sum_{k>r} S[k][r]*Xm[k]
            #pragma unroll 1
            for (int r = 30; r >= 0; --r) {
                float acc = 0.f;
                #pragma unroll 4
                for (int k = r+1; k < 32; ++k) acc += s.S[k][r] * s.Xm[k][lane];
                s.Xm[r][lane] -= s.dinv[r] * acc;
            }
            float accz = 0.f;
            #pragma unroll 4
            for (int r = 0; r < 32; ++r) accz += s.Xm[r][lane] * s.rvec[r];
            s.zn[lane] = s.zp[lane] + mkv * accz;
        } else {
            // 192 threads, 384 gates: speculative gi (x with a_k) + gh
            #pragma unroll 1
            for (int g = tid - 64; g < 3*HG; g += 192) {
                const float* wi = W_ih + (size_t)g * DINc;
                const float* wh = W_hh + (size_t)g * HG;
                f4 ai = {0.f,0.f,0.f,0.f}, ah = {0.f,0.f,0.f,0.f};
                #pragma unroll 7
                for (int q = 0; q < 14; ++q) ai += *(const f4*)(wi + q*4) * *(const f4*)&s.x[q*4];
                #pragma unroll 8
                for (int q = 0; q < 32; ++q) ah += *(const f4*)(wh + q*4) * *(const f4*)&s.h[q*4];
                s.gi[g] = ai[0]+ai[1]+ai[2]+ai[3] + b_ih[g];
                s.gh[g] = ah[0]+ah[1]+ah[2]+ah[3] + b_hh[g];
            }
        }
        __syncthreads();

        // ---- P4: G = X^T CP -> Wk ; z_filt emits ----
        {
            float acc[4][4] = {{0.f,0.f,0.f,0.f},{0.f,0.f,0.f,0.f},{0.f,0.f,0.f,0.f},{0.f,0.f,0.f,0.f}};
            #pragma unroll 4
            for (int l = 0; l < DAc; ++l) {
                f4 bv = *(const f4*)&s.CP[l][c4];
                float a0 = s.Xm[l][r4], a1 = s.Xm[l][r4+1], a2 = s.Xm[l][r4+2], a3 = s.Xm[l][r4+3];
                #pragma unroll
                for (int j = 0; j < 4; ++j) {
                    acc[0][j] += a0*bv[j]; acc[1][j] += a1*bv[j];
                    acc[2][j] += a2*bv[j]; acc[3][j] += a3*bv[j];
                }
            }
            #pragma unroll
            for (int i = 0; i < 4; ++i) {
                f4 v = {acc[i][0],acc[i][1],acc[i][2],acc[i][3]};
                *(f4*)&s.Wk[r4+i][c4] = v;
            }
        }
        if (tid < DZc) {
            float v = s.zn[tid];
            out[O_ZFILT + bt*DZc + tid] = v;
            out[O_ZMEAN + bt*DZc + tid] = v;
            s.z[tid] = v;
        }
        __syncthreads();

        // ---- P5: P_filt = P + (mk^2-2mk) sym(G) + emit ; a_filt ; x ; C_seq ; (mk1: h) ----
        {
            const float coef = (mkv*mkv - 2.f*mkv) * 0.5f;
            #pragma unroll
            for (int i = 0; i < 4; ++i) {
                f4 grow = *(const f4*)&s.Wk[r4+i][c4];
                f4 p = *(const f4*)&s.P[r4+i][c4];
                f4 v;
                #pragma unroll
                for (int j = 0; j < 4; ++j)
                    v[j] = p[j] + coef * (grow[j] + s.Wk[c4+j][r4+i]);
                *(f4*)&s.P[r4+i][c4] = v;
                *(f4*)&out[O_PFILT + bt*4096 + (size_t)(r4+i)*64 + c4] = v;
            }
        }
        if (tid < DAc) {
            float acc = 0.f;
            #pragma unroll 4
            for (int k4 = 0; k4 < 16; ++k4)
                acc += dot4(*(const f4*)&s.C[tid][k4*4], *(const f4*)&s.zn[k4*4]);
            out[O_AFILT + bt*DAc + tid] = acc;
            s.x[tid] = mkv * s.ak[tid] + (1.f - mkv) * acc;   // a_k_hat (true)
        }
        #pragma unroll 1
        for (int e = 0; e < 2; ++e) {
            int i4 = tid + e*256;
            *(f4*)&out[O_CSEQ + bt*2048 + (size_t)i4*4] = *(const f4*)&s.C[i4>>4][(i4&15)*4];
        }
        if (mk1 && tid < HG) {
            float gi0 = s.gi[tid], gi1 = s.gi[HG+tid], gi2 = s.gi[2*HG+tid];
            float gh0 = s.gh[tid], gh1 = s.gh[HG+tid], gh2 = s.gh[2*HG+tid];
            float hold = s.h[tid];
            float r  = 1.f / (1.f + expf(-(gi0 + gh0)));
            float zg = 1.f / (1.f + expf(-(gi1 + gh1)));
            float n  = tanhf(gi2 + r * gh2);
            s.h[tid] = (1.f - zg) * n + zg * hold;
        }
        __syncthreads();

        if (!mk1) {
            // recompute gi with the true a_k_hat, then h-update
            for (int g = tid; g < 3*HG; g += NT) {
                const float* wi = W_ih + (size_t)g * DINc;
                f4 ai = {0.f,0.f,0.f,0.f};
                #pragma unroll 7
                for (int q = 0; q < 14; ++q) ai += *(const f4*)(wi + q*4) * *(const f4*)&s.x[q*4];
                s.gi[g] = ai[0]+ai[1]+ai[2]+ai[3] + b_ih[g];
            }
            __syncthreads();
            if (tid < HG) {
                float gi0 = s.gi[tid], gi1 = s.gi[HG+tid], gi2 = s.gi[2*HG+tid];
                float gh0 = s.gh[tid], gh1 = s.gh[HG+tid], gh2 = s.gh[2*HG+tid];
                float hold = s.h[tid];
                float r  = 1.f / (1.f + expf(-(gi0 + gh0)));
                float zg = 1.f / (1.f + expf(-(gi1 + gh1)));
                float n  = tanhf(gi2 + r * gh2);
                s.h[tid] = (1.f - zg) * n + zg * hold;
            }
            __syncthreads();
        }

        // ---- P6a: logits (8 plain dots, no shuffles) ----
        if (tid < KMIX) {
            const float* wo = W_out + tid * HG;
            f4 acc = {0.f,0.f,0.f,0.f};
            #pragma unroll 8
            for (int q = 0; q < 32; ++q) acc += *(const f4*)(wo + q*4) * *(const f4*)&s.h[q*4];
            s.lg[tid] = acc[0]+acc[1]+acc[2]+acc[3] + b_out[tid];
        }
        __syncthreads();

        // ---- P6b: softmax (replicated) + mix + emits ----
        {
            float lg[8];
            #pragma unroll
            for (int k = 0; k < 8; ++k) lg[k] = s.lg[k];
            float mx = lg[0];
            #pragma unroll
            for (int k = 1; k < 8; ++k) mx = fmaxf(mx, lg[k]);
            float al[8]; float sum = 0.f;
            #pragma unroll
            for (int k = 0; k < 8; ++k) { al[k] = expf(lg[k] - mx); sum += al[k]; }
            float rs = 1.f / sum;
            #pragma unroll
            for (int k = 0; k < 8; ++k) al[k] *= rs;
            if (tid < 8) out[O_ALPHA + bt*8 + tid] = al[tid];
            mix_apply<true>(s, tid, bt, al, A_mats, B_mats, C_mats, out);
        }
        __syncthreads();

        // ---- P7: Wk = A_new @ P_filt ; z_pred ----
        if (tid < DZc) {
            float acc = 0.f;
            #pragma unroll 4
            for (int k4 = 0; k4 < 16; ++k4)
                acc += dot4(*(const f4*)&s.A[tid][k4*4], *(const f4*)&s.z[k4*4]);
            acc += dot4(*(const f4*)&s.Bm[tid][0], *(const f4*)&s.u[0]);
            acc += dot4(*(const f4*)&s.Bm[tid][4], *(const f4*)&s.u[4]);
            s.zp[tid] = acc;
            out[O_ZPRED + bt*DZc + tid] = acc;
        }
        {
            float acc[4][4] = {{0.f,0.f,0.f,0.f},{0.f,0.f,0.f,0.f},{0.f,0.f,0.f,0.f},{0.f,0.f,0.f,0.f}};
            #pragma unroll 2
            for (int k4 = 0; k4 < 16; ++k4) {
                #pragma unroll
                for (int kk = 0; kk < 4; ++kk) {
                    f4 bv = *(const f4*)&s.P[k4*4+kk][c4];
                    #pragma unroll
                    for (int i = 0; i < 4; ++i) {
                        float av = s.A[r4+i][k4*4+kk];
                        #pragma unroll
                        for (int j = 0; j < 4; ++j) acc[i][j] += av * bv[j];
                    }
                }
            }
            #pragma unroll
            for (int i = 0; i < 4; ++i) {
                f4 v = {acc[i][0],acc[i][1],acc[i][2],acc[i][3]};
                *(f4*)&s.Wk[r4+i][c4] = v;
            }
        }
        __syncthreads();

        // ---- P8: P_pred = Wk @ A^T + Q -> s.P + coalesced emit ; a_pred ----
        {
            float acc[4][4] = {{0.f,0.f,0.f,0.f},{0.f,0.f,0.f,0.f},{0.f,0.f,0.f,0.f},{0.f,0.f,0.f,0.f}};
            #pragma unroll 2
            for (int k4 = 0; k4 < 16; ++k4) {
                f4 w0 = *(const f4*)&s.Wk[r4+0][k4*4];
                f4 w1 = *(const f4*)&s.Wk[r4+1][k4*4];
                f4 w2 = *(const f4*)&s.Wk[r4+2][k4*4];
                f4 w3 = *(const f4*)&s.Wk[r4+3][k4*4];
                #pragma unroll
                for (int j = 0; j < 4; ++j) {
                    f4 a = *(const f4*)&s.A[c4+j][k4*4];
                    acc[0][j] += dot4(w0,a); acc[1][j] += dot4(w1,a);
                    acc[2][j] += dot4(w2,a); acc[3][j] += dot4(w3,a);
                }
            }
            #pragma unroll
            for (int i = 0; i < 4; ++i) {
                f4 q = *(const f4*)&s.Qm[r4+i][c4];
                f4 v = {acc[i][0]+q[0],acc[i][1]+q[1],acc[i][2]+q[2],acc[i][3]+q[3]};
                *(f4*)&s.P[r4+i][c4] = v;
                *(f4*)&out[O_PPRED + bt*4096 + (size_t)(r4+i)*64 + c4] = v;
            }
        }
        if (tid < DAc) {
            float acc = 0.f;
            #pragma unroll 4
            for (int k4 = 0; k4 < 16; ++k4)
                acc += dot4(*(const f4*)&s.C[tid][k4*4], *(const f4*)&s.zp[k4*4]);
            out[O_APRED + bt*DAc + tid] = acc;
        }
        __syncthreads();
    }
}

// ---- kernel 2: batched 64x64 Cholesky for z_scale_tril (off the sequential path) ----
__global__ void __launch_bounds__(64, 4)
chol_batch(float* __restrict__ out)
{
    __shared__ float M[DZc][68];
    const size_t bt = blockIdx.x;
    const int lane = threadIdx.x;
    const float* src = out + O_PFILT + bt*4096;
    #pragma unroll 4
    for (int e = 0; e < 16; ++e) {
        int i4 = lane + e*64;
        f4 v = *(const f4*)(src + (size_t)i4*4);
        *(f4*)&M[i4>>4][(i4&15)*4] = v;
    }
    __syncthreads();
    float row[64];
    #pragma unroll 8
    for (int k = 0; k < 64; ++k) row[k] = M[lane][k];
    row[lane] += 2.0e-4f;   // + 2*JITTER
    #pragma unroll 1
    for (int k = 0; k < 64; ++k) {
        float acc = row[k];
        for (int m = 0; m < k; ++m) acc -= row[m] * __shfl(row[m], k);
        float d = sqrtf(__shfl(acc, k));
        float inv = 1.0f / d;
        row[k] = (lane == k) ? d : acc * inv;
    }
    #pragma unroll 8
    for (int k = 0; k < 64; ++k) M[lane][k] = (k <= lane) ? row[k] : 0.f;
    __syncthreads();
    float* dst = out + O_LTRIL + bt*4096;
    #pragma unroll 4
    for (int e = 0; e < 16; ++e) {
        int i4 = lane + e*64;
        *(f4*)(dst + (size_t)i4*4) = *(const f4*)&M[i4>>4][(i4&15)*4];
    }
}

extern "C" void kernel_launch(void* const* d_in, const int* in_sizes, int n_in,
                              void* d_out, int out_size, void* d_ws, size_t ws_size,
                              hipStream_t stream) {
    const float* a_seq  = (const float*)d_in[0];
    const float* h_obs  = (const float*)d_in[1];
    const float* u_seq  = (const float*)d_in[2];
    const float* mask   = (const float*)d_in[3];
    const float* A_mats = (const float*)d_in[4];
    const float* B_mats = (const float*)d_in[5];
    const float* C_mats = (const float*)d_in[6];
    const float* a_0    = (const float*)d_in[7];
    const float* P_0    = (const float*)d_in[8];
    const float* Q      = (const float*)d_in[9];
    const float* R      = (const float*)d_in[10];
    const float* W_ih   = (const float*)d_in[11];
    const float* W_hh   = (const float*)d_in[12];
    const float* b_ih   = (const float*)d_in[13];
    const float* b_hh   = (const float*)d_in[14];
    const float* W_out  = (const float*)d_in[15];
    const float* b_out  = (const float*)d_in[16];
    float* out = (float*)d_out;

    kalman_seq<<<dim3(BB), dim3(NT), 0, stream>>>(a_seq, h_obs, u_seq, mask,
        A_mats, B_mats, C_mats, a_0, P_0, Q, R, W_ih, W_hh, b_ih, b_hh, W_out, b_out, out);
    chol_batch<<<dim3(BB*BT), dim3(64), 0, stream>>>(out);
}